// Round 7
// baseline (110.996 us; speedup 1.0000x reference)
//
#include <hip/hip_runtime.h>
#include <math.h>

#define NN 8
#define CC 96
#define HH 256
#define WW 256
#define GG 2
#define KK 3
#define CPG (CC / GG)
#define HWD (HH * WW)
#define CHUNKS 8   // mean-pass chunks per (n,c) slice

typedef float fvec4 __attribute__((ext_vector_type(4)));

// ---------------------------------------------------------------------------
// Kernel A: partial sums. 6144 blocks (8 per (n,c) slice), 256 threads.
// Regular loads ON PURPOSE: they allocate x into the 256 MiB L3 so kernel B's
// reads hit.
// ---------------------------------------------------------------------------
__global__ __launch_bounds__(256) void partial_kernel(
    const float* __restrict__ x, float* __restrict__ mp) {
    const int b = blockIdx.x;           // 0 .. NN*CC*CHUNKS-1
    const int nc = b >> 3;
    const int chunk = b & 7;
    const int t = threadIdx.x;
    const fvec4* xp = (const fvec4*)x + (size_t)nc * (HWD / 4)
                      + (size_t)chunk * (HWD / 4 / CHUNKS);
    float s = 0.f;
#pragma unroll
    for (int i = 0; i < HWD / 4 / CHUNKS / 256; ++i) {  // 8 iters
        fvec4 v = xp[i * 256 + t];
        s += (v.x + v.y) + (v.z + v.w);
    }
#pragma unroll
    for (int off = 32; off; off >>= 1) s += __shfl_down(s, off, 64);
    __shared__ float ls[4];
    if ((t & 63) == 0) ls[t >> 6] = s;
    __syncthreads();
    if (t == 0) mp[b] = (ls[0] + ls[1]) + (ls[2] + ls[3]);
}

// ---------------------------------------------------------------------------
// Kernel B: main pass. 12288 blocks; each block owns 16 rows of one (n,c).
// INVERTED cache policy vs R5: x-reads are NON-TEMPORAL (hit the L3 copy A
// left behind, no re-allocation on miss), out-stores are REGULAR (full-rate
// store stream). Capacity: live x (192(1-p) MiB) + out (192p MiB) = 192 MiB
// < 256 MiB L3 at all times, so x hits should survive out's allocations.
// ---------------------------------------------------------------------------
__global__ __launch_bounds__(256) void main_kernel(
    const float* __restrict__ x, const float* __restrict__ mp,
    const float* __restrict__ Wconv, const float* __restrict__ inside_all,
    const float* __restrict__ lamb_l, const float* __restrict__ lamb_h,
    float* __restrict__ out) {
    const int bb = blockIdx.x;
    const int nc = bb >> 4;             // HH/16 = 16 blocks per (n,c)
    const int rblk = bb & 15;
    const int t = threadIdx.x;
    const int wave = t >> 6;
    const int lane = t & 63;
    const int c = nc % CC;
    const int n = nc / CC;
    const int g = c / CPG;

    // ---- Prologue: per-channel mean sums -> LDS, then 3 taps ----
    __shared__ float msh[CC];
    __shared__ float fsh[KK];
    if (t < CC) {
        const float* pr = mp + ((size_t)n * CC + t) * CHUNKS;
        float a0 = 0.f;
#pragma unroll
        for (int k = 0; k < CHUNKS; ++k) a0 += pr[k];
        msh[t] = a0;
    }
    __syncthreads();
    if (t < KK) {
        const float* Wr = Wconv + (g * KK + t) * CC;
        float acc = 0.f;
#pragma unroll
        for (int j = 0; j < CC; ++j) acc += msh[j] * Wr[j];
        fsh[t] = tanhf(acc * (1.0f / (float)HWD));
    }
    __syncthreads();
    const float f0 = fsh[0], f1 = fsh[1], f2 = fsh[2];
    const float ia = inside_all[c];
    const float ll = lamb_l[c];
    const float lh1 = lamb_h[c] + 1.0f;
    const float a = ia + 1.0f;

    // ---- 4 rows per wave, interleaved chains ----
    const int row0 = (rblk << 4) + (wave << 2);
    const size_t base = ((size_t)nc * HH + row0) * WW;
    fvec4 v0 = __builtin_nontemporal_load((const fvec4*)(x + base + 0 * WW) + lane);
    fvec4 v1 = __builtin_nontemporal_load((const fvec4*)(x + base + 1 * WW) + lane);
    fvec4 v2 = __builtin_nontemporal_load((const fvec4*)(x + base + 2 * WW) + lane);
    fvec4 v3 = __builtin_nontemporal_load((const fvec4*)(x + base + 3 * WW) + lane);

    float s0 = (v0.x + v0.y) + (v0.z + v0.w);
    float s1 = (v1.x + v1.y) + (v1.z + v1.w);
    float s2 = (v2.x + v2.y) + (v2.z + v2.w);
    float s3 = (v3.x + v3.y) + (v3.z + v3.w);
#pragma unroll
    for (int off = 1; off < 64; off <<= 1) {
        s0 += __shfl_xor(s0, off, 64);
        s1 += __shfl_xor(s1, off, 64);
        s2 += __shfl_xor(s2, off, 64);
        s3 += __shfl_xor(s3, off, 64);
    }

#pragma unroll
    for (int r = 0; r < 4; ++r) {
        const fvec4 v = (r == 0) ? v0 : (r == 1) ? v1 : (r == 2) ? v2 : v3;
        const float rs = (r == 0) ? s0 : (r == 1) ? s1 : (r == 2) ? s2 : s3;
        const float gap = rs * (1.0f / (float)WW);

        const float left = __shfl_up(v.w, 1, 64);
        const float right = __shfl_down(v.x, 1, 64);
        const float xm1 = (lane == 0) ? v.y : left;    // reflect: x[-1]=x[1]
        const float xp1 = (lane == 63) ? v.z : right;  // reflect: x[W]=x[W-2]

        const float c0 = f0 * xm1 + f1 * v.x + f2 * v.y;
        const float c1 = f0 * v.x + f1 * v.y + f2 * v.z;
        const float c2 = f0 * v.y + f1 * v.z + f2 * v.w;
        const float c3 = f0 * v.z + f1 * v.w + f2 * xp1;

        const float bterm = ia * gap;
        fvec4 o;
        o.x = (c0 * a - bterm) * ll + v.x * lh1;
        o.y = (c1 * a - bterm) * ll + v.y * lh1;
        o.z = (c2 * a - bterm) * ll + v.z * lh1;
        o.w = (c3 * a - bterm) * ll + v.w * lh1;
        ((fvec4*)(out + base + r * WW))[lane] = o;  // REGULAR store
    }
}

// ---------------------------------------------------------------------------
extern "C" void kernel_launch(void* const* d_in, const int* in_sizes, int n_in,
                              void* d_out, int out_size, void* d_ws,
                              size_t ws_size, hipStream_t stream) {
    const float* x = (const float*)d_in[0];
    const float* Wconv = (const float*)d_in[1];
    const float* inside_all = (const float*)d_in[2];
    const float* lamb_l = (const float*)d_in[3];
    const float* lamb_h = (const float*)d_in[4];
    float* out = (float*)d_out;
    float* mp = (float*)d_ws;  // NN*CC*CHUNKS raw partial sums

    partial_kernel<<<NN * CC * CHUNKS, 256, 0, stream>>>(x, mp);
    main_kernel<<<NN * CC * (HH / 16), 256, 0, stream>>>(
        x, mp, Wconv, inside_all, lamb_l, lamb_h, out);
}